// Round 1
// baseline (153.708 us; speedup 1.0000x reference)
//
#include <hip/hip_runtime.h>
#include <math.h>

#define Cch 64
#define Gg  4
#define Hh  256
#define Ww  256

__device__ __forceinline__ float mishf(float x) {
    // mish(x) = x * tanh(softplus(x)) = x * ((1+e^x)^2 - 1) / ((1+e^x)^2 + 1)
    float e  = __expf(fminf(x, 15.0f));   // clamp: tanh(softplus(15)) == 1 in fp32
    float n  = 1.0f + e;
    float n2 = n * n;
    float t  = __fdividef(n2 - 1.0f, n2 + 1.0f);
    return x > 15.0f ? x : x * t;
}

__global__ __launch_bounds__(256) void revo_kernel(
    const float* __restrict__ in,
    const float* __restrict__ w1, const float* __restrict__ b1,
    const float* __restrict__ w2, const float* __restrict__ b2,
    const float* __restrict__ w3, const float* __restrict__ b3,
    const float* __restrict__ gamma, const float* __restrict__ beta,
    const float* __restrict__ mean,  const float* __restrict__ var,
    float* __restrict__ out)
{
    const int w = threadIdx.x;                 // 0..255  (pixel column)
    const int h = blockIdx.x & (Hh - 1);       // row
    const int b = blockIdx.x >> 8;             // batch

    const float* base = in + (size_t)b * Cch * Hh * Ww;

    const bool okm = (w > 0);
    const bool okp = (w < Ww - 1);
    const int offm = okm ? -1 : 0;
    const int offp = okp ?  1 : 0;

    // conv1 accumulators (16 outputs), init with bias
    float y[16];
    #pragma unroll
    for (int o = 0; o < 16; ++o) y[o] = b1[o];

    float gmax[9];

    // ---- pass 1: patch gather + multi-axis maxes fused into conv1 ----
    for (int c = 0; c < Cch; ++c) {
        float p[9];
        #pragma unroll
        for (int kh = 0; kh < 3; ++kh) {
            int hh = h + kh - 1;
            bool okh = (hh >= 0) && (hh < Hh);
            int hhc = hh < 0 ? 0 : (hh > Hh - 1 ? Hh - 1 : hh);
            const float* rp = base + ((size_t)c * Hh + hhc) * Ww + w;
            float v0 = rp[offm];
            float v1 = rp[0];
            float v2 = rp[offp];
            p[kh * 3 + 0] = (okh && okm) ? v0 : 0.0f;
            p[kh * 3 + 1] = okh ? v1 : 0.0f;
            p[kh * 3 + 2] = (okh && okp) ? v2 : 0.0f;
        }
        // m_kh[kw] = max over rows; m_kw[kh] = max over cols
        float mkh0 = fmaxf(fmaxf(p[0], p[3]), p[6]);
        float mkh1 = fmaxf(fmaxf(p[1], p[4]), p[7]);
        float mkh2 = fmaxf(fmaxf(p[2], p[5]), p[8]);
        float mkw0 = fmaxf(fmaxf(p[0], p[1]), p[2]);
        float mkw1 = fmaxf(fmaxf(p[3], p[4]), p[5]);
        float mkw2 = fmaxf(fmaxf(p[6], p[7]), p[8]);

        if ((c & 15) == 0) {
            #pragma unroll
            for (int k = 0; k < 9; ++k) gmax[k] = p[k];
        } else {
            #pragma unroll
            for (int k = 0; k < 9; ++k) gmax[k] = fmaxf(gmax[k], p[k]);
        }

        // conv1 partial: channels 36 + c*3 + kw (m_kh) and 228 + c*3 + kh (m_kw)
        #pragma unroll
        for (int o = 0; o < 16; ++o) {
            const float* r = w1 + o * 420;
            y[o] = fmaf(r[ 36 + c * 3 + 0], mkh0, y[o]);
            y[o] = fmaf(r[ 36 + c * 3 + 1], mkh1, y[o]);
            y[o] = fmaf(r[ 36 + c * 3 + 2], mkh2, y[o]);
            y[o] = fmaf(r[228 + c * 3 + 0], mkw0, y[o]);
            y[o] = fmaf(r[228 + c * 3 + 1], mkw1, y[o]);
            y[o] = fmaf(r[228 + c * 3 + 2], mkw2, y[o]);
        }
        if ((c & 15) == 15) {
            int g = c >> 4;   // group finished: flush m_gc part (channels g*9+k)
            #pragma unroll
            for (int o = 0; o < 16; ++o) {
                const float* r = w1 + o * 420 + g * 9;
                #pragma unroll
                for (int k = 0; k < 9; ++k)
                    y[o] = fmaf(r[k], gmax[k], y[o]);
            }
        }
    }

    // ---- mish(conv1) ----
    float feat[16];
    #pragma unroll
    for (int o = 0; o < 16; ++o) feat[o] = mishf(y[o]);

    // ---- conv2 (center tap only, NS=1) + BN + mish gate ----
    float feat2[16];
    #pragma unroll
    for (int o = 0; o < 16; ++o) {
        float acc = b2[o];
        #pragma unroll
        for (int i = 0; i < 16; ++i)
            acc = fmaf(w2[o * 144 + i * 9 + 4], feat[i], acc);
        float sc = gamma[o] * rsqrtf(var[o] + 1e-5f);
        acc = acc * sc + (beta[o] - mean[o] * sc);
        feat2[o] = feat[o] * mishf(acc);
    }

    // ---- conv3 (16 -> 36) + per-group softmax over 9 taps ----
    float att[4][9];
    #pragma unroll
    for (int g = 0; g < 4; ++g) {
        float l[9];
        float mx = -1e30f;
        #pragma unroll
        for (int k = 0; k < 9; ++k) {
            float acc = b3[g * 9 + k];
            #pragma unroll
            for (int i = 0; i < 16; ++i)
                acc = fmaf(w3[(g * 9 + k) * 16 + i], feat2[i], acc);
            l[k] = acc;
            mx = fmaxf(mx, acc);
        }
        float s = 0.0f;
        #pragma unroll
        for (int k = 0; k < 9; ++k) { l[k] = __expf(l[k] - mx); s += l[k]; }
        float inv = __fdividef(1.0f, s);
        #pragma unroll
        for (int k = 0; k < 9; ++k) att[g][k] = l[k] * inv;
    }

    // ---- pass E: softmax-weighted patch aggregation ----
    float* ob = out + (((size_t)b * Cch) * Hh + h) * Ww + w;
    #pragma unroll
    for (int g = 0; g < 4; ++g) {
        for (int gc = 0; gc < 16; ++gc) {
            int c = g * 16 + gc;
            float acc = 0.0f;
            #pragma unroll
            for (int kh = 0; kh < 3; ++kh) {
                int hh = h + kh - 1;
                bool okh = (hh >= 0) && (hh < Hh);
                int hhc = hh < 0 ? 0 : (hh > Hh - 1 ? Hh - 1 : hh);
                const float* rp = base + ((size_t)c * Hh + hhc) * Ww + w;
                float v0 = rp[offm];
                float v1 = rp[0];
                float v2 = rp[offp];
                v0 = (okh && okm) ? v0 : 0.0f;
                v1 = okh ? v1 : 0.0f;
                v2 = (okh && okp) ? v2 : 0.0f;
                acc = fmaf(v0, att[g][kh * 3 + 0], acc);
                acc = fmaf(v1, att[g][kh * 3 + 1], acc);
                acc = fmaf(v2, att[g][kh * 3 + 2], acc);
            }
            ob[(size_t)c * Hh * Ww] = acc;
        }
    }
}

extern "C" void kernel_launch(void* const* d_in, const int* in_sizes, int n_in,
                              void* d_out, int out_size, void* d_ws, size_t ws_size,
                              hipStream_t stream) {
    const float* in    = (const float*)d_in[0];
    const float* w1    = (const float*)d_in[1];
    const float* b1    = (const float*)d_in[2];
    const float* w2    = (const float*)d_in[3];
    const float* b2    = (const float*)d_in[4];
    const float* w3    = (const float*)d_in[5];
    const float* b3    = (const float*)d_in[6];
    const float* gamma = (const float*)d_in[7];
    const float* beta  = (const float*)d_in[8];
    const float* mean  = (const float*)d_in[9];
    const float* var   = (const float*)d_in[10];
    float* out = (float*)d_out;

    dim3 grid(2 * Hh);   // B * H = 512 blocks
    dim3 block(Ww);      // 256 threads, one pixel per thread
    hipLaunchKernelGGL(revo_kernel, grid, block, 0, stream,
                       in, w1, b1, w2, b2, w3, b3, gamma, beta, mean, var, out);
}

// Round 2
// 92.374 us; speedup vs baseline: 1.6640x; 1.6640x over previous
//
#include <hip/hip_runtime.h>
#include <math.h>

#define Cch 64
#define Hh  256
#define Ww  256

__device__ __forceinline__ float mishf(float x) {
    // mish(x) = x * tanh(softplus(x)) = x * ((1+e^x)^2 - 1) / ((1+e^x)^2 + 1)
    float e  = __expf(fminf(x, 15.0f));   // clamp: tanh(softplus(15)) == 1 in fp32
    float n  = 1.0f + e;
    float n2 = n * n;
    float t  = __fdividef(n2 - 1.0f, n2 + 1.0f);
    return x > 15.0f ? x : x * t;
}

// Block = 256 threads = 4 waves. Wave g (g=0..3) handles channel-group g for
// 64 pixels (one 64-wide column segment of one row). Weight accesses are
// wave-uniform -> scalar loads. Partial conv1 sums exchanged through LDS.
__global__ __launch_bounds__(256, 8) void revo_kernel(
    const float* __restrict__ in,
    const float* __restrict__ w1, const float* __restrict__ b1,
    const float* __restrict__ w2, const float* __restrict__ b2,
    const float* __restrict__ w3, const float* __restrict__ b3,
    const float* __restrict__ gamma, const float* __restrict__ beta,
    const float* __restrict__ mean,  const float* __restrict__ var,
    float* __restrict__ out)
{
    const int tid  = threadIdx.x;
    const int g    = __builtin_amdgcn_readfirstlane(tid >> 6);   // wave-uniform group id
    const int lane = tid & 63;

    const int wseg = blockIdx.x & 3;              // which 64-col segment
    const int h    = (blockIdx.x >> 2) & (Hh - 1);
    const int b    = blockIdx.x >> 10;

    const int w = wseg * 64 + lane;               // pixel column 0..255

    __shared__ float lds_y[4][64][17];            // stride 17: conflict-free

    const float* base = in + (size_t)b * Cch * Hh * Ww;

    const bool okm = (w > 0);
    const bool okp = (w < Ww - 1);
    const int offm = okm ? -1 : 0;
    const int offp = okp ?  1 : 0;

    // row validity / clamped row indices (uniform)
    const int hm  = h - 1, hp = h + 1;
    const bool okhm = (hm >= 0), okhp = (hp < Hh);
    const int hmc = okhm ? hm : 0;
    const int hpc = okhp ? hp : Hh - 1;

    // ---- phase 1: this wave's 16 channels of conv1 partial sums ----
    float y[16];
    #pragma unroll
    for (int o = 0; o < 16; ++o) y[o] = 0.0f;
    float gmax[9];

    for (int cc = 0; cc < 16; ++cc) {
        const int c = (g << 4) + cc;              // wave-uniform channel
        const float* cb = base + (size_t)c * Hh * Ww;
        float p[9];
        {
            const float* rp = cb + (size_t)hmc * Ww + w;
            float v0 = rp[offm], v1 = rp[0], v2 = rp[offp];
            p[0] = (okhm && okm) ? v0 : 0.0f;
            p[1] = okhm ? v1 : 0.0f;
            p[2] = (okhm && okp) ? v2 : 0.0f;
        }
        {
            const float* rp = cb + (size_t)h * Ww + w;
            float v0 = rp[offm], v1 = rp[0], v2 = rp[offp];
            p[3] = okm ? v0 : 0.0f;
            p[4] = v1;
            p[5] = okp ? v2 : 0.0f;
        }
        {
            const float* rp = cb + (size_t)hpc * Ww + w;
            float v0 = rp[offm], v1 = rp[0], v2 = rp[offp];
            p[6] = (okhp && okm) ? v0 : 0.0f;
            p[7] = okhp ? v1 : 0.0f;
            p[8] = (okhp && okp) ? v2 : 0.0f;
        }

        float mkh0 = fmaxf(fmaxf(p[0], p[3]), p[6]);
        float mkh1 = fmaxf(fmaxf(p[1], p[4]), p[7]);
        float mkh2 = fmaxf(fmaxf(p[2], p[5]), p[8]);
        float mkw0 = fmaxf(fmaxf(p[0], p[1]), p[2]);
        float mkw1 = fmaxf(fmaxf(p[3], p[4]), p[5]);
        float mkw2 = fmaxf(fmaxf(p[6], p[7]), p[8]);

        if (cc == 0) {
            #pragma unroll
            for (int k = 0; k < 9; ++k) gmax[k] = p[k];
        } else {
            #pragma unroll
            for (int k = 0; k < 9; ++k) gmax[k] = fmaxf(gmax[k], p[k]);
        }

        // m_kh channels: 36 + c*3 + kw ; m_kw channels: 228 + c*3 + kh
        #pragma unroll
        for (int o = 0; o < 16; ++o) {
            const float* r = w1 + o * 420;
            y[o] = fmaf(r[ 36 + c * 3 + 0], mkh0, y[o]);
            y[o] = fmaf(r[ 36 + c * 3 + 1], mkh1, y[o]);
            y[o] = fmaf(r[ 36 + c * 3 + 2], mkh2, y[o]);
            y[o] = fmaf(r[228 + c * 3 + 0], mkw0, y[o]);
            y[o] = fmaf(r[228 + c * 3 + 1], mkw1, y[o]);
            y[o] = fmaf(r[228 + c * 3 + 2], mkw2, y[o]);
        }
    }
    // m_gc flush for this wave's group: channels g*9 + k
    #pragma unroll
    for (int o = 0; o < 16; ++o) {
        const float* r = w1 + o * 420 + g * 9;
        #pragma unroll
        for (int k = 0; k < 9; ++k)
            y[o] = fmaf(r[k], gmax[k], y[o]);
    }

    // ---- exchange partial sums ----
    #pragma unroll
    for (int o = 0; o < 16; ++o) lds_y[g][lane][o] = y[o];
    __syncthreads();

    // ---- phase 2: reduce + mish(conv1) (redundant across the 4 waves) ----
    float feat[16];
    #pragma unroll
    for (int o = 0; o < 16; ++o) {
        float t = lds_y[0][lane][o] + lds_y[1][lane][o]
                + lds_y[2][lane][o] + lds_y[3][lane][o] + b1[o];
        feat[o] = mishf(t);
    }

    // ---- conv2 (center tap, NS=1) + BN + mish gate ----
    float feat2[16];
    #pragma unroll
    for (int o = 0; o < 16; ++o) {
        float acc = b2[o];
        #pragma unroll
        for (int i = 0; i < 16; ++i)
            acc = fmaf(w2[o * 144 + i * 9 + 4], feat[i], acc);
        float sc = gamma[o] * rsqrtf(var[o] + 1e-5f);
        acc = acc * sc + (beta[o] - mean[o] * sc);
        feat2[o] = feat[o] * mishf(acc);
    }

    // ---- conv3 for THIS group's 9 logits + softmax ----
    float att[9];
    {
        float mx = -1e30f;
        #pragma unroll
        for (int k = 0; k < 9; ++k) {
            float acc = b3[g * 9 + k];
            #pragma unroll
            for (int i = 0; i < 16; ++i)
                acc = fmaf(w3[(g * 9 + k) * 16 + i], feat2[i], acc);
            att[k] = acc;
            mx = fmaxf(mx, acc);
        }
        float s = 0.0f;
        #pragma unroll
        for (int k = 0; k < 9; ++k) { att[k] = __expf(att[k] - mx); s += att[k]; }
        float inv = __fdividef(1.0f, s);
        #pragma unroll
        for (int k = 0; k < 9; ++k) att[k] *= inv;
    }

    // ---- aggregation over THIS group's 16 channels ----
    float* ob = out + (((size_t)b * Cch) * Hh + h) * Ww + w;
    for (int gc = 0; gc < 16; ++gc) {
        const int c = (g << 4) + gc;
        const float* cb = base + (size_t)c * Hh * Ww;
        float acc = 0.0f;
        {
            const float* rp = cb + (size_t)hmc * Ww + w;
            float v0 = rp[offm], v1 = rp[0], v2 = rp[offp];
            acc = fmaf((okhm && okm) ? v0 : 0.0f, att[0], acc);
            acc = fmaf(okhm ? v1 : 0.0f,          att[1], acc);
            acc = fmaf((okhm && okp) ? v2 : 0.0f, att[2], acc);
        }
        {
            const float* rp = cb + (size_t)h * Ww + w;
            float v0 = rp[offm], v1 = rp[0], v2 = rp[offp];
            acc = fmaf(okm ? v0 : 0.0f, att[3], acc);
            acc = fmaf(v1,              att[4], acc);
            acc = fmaf(okp ? v2 : 0.0f, att[5], acc);
        }
        {
            const float* rp = cb + (size_t)hpc * Ww + w;
            float v0 = rp[offm], v1 = rp[0], v2 = rp[offp];
            acc = fmaf((okhp && okm) ? v0 : 0.0f, att[6], acc);
            acc = fmaf(okhp ? v1 : 0.0f,          att[7], acc);
            acc = fmaf((okhp && okp) ? v2 : 0.0f, att[8], acc);
        }
        ob[(size_t)c * Hh * Ww] = acc;
    }
}

extern "C" void kernel_launch(void* const* d_in, const int* in_sizes, int n_in,
                              void* d_out, int out_size, void* d_ws, size_t ws_size,
                              hipStream_t stream) {
    const float* in    = (const float*)d_in[0];
    const float* w1    = (const float*)d_in[1];
    const float* b1    = (const float*)d_in[2];
    const float* w2    = (const float*)d_in[3];
    const float* b2    = (const float*)d_in[4];
    const float* w3    = (const float*)d_in[5];
    const float* b3    = (const float*)d_in[6];
    const float* gamma = (const float*)d_in[7];
    const float* beta  = (const float*)d_in[8];
    const float* mean  = (const float*)d_in[9];
    const float* var   = (const float*)d_in[10];
    float* out = (float*)d_out;

    // B * H * (W/64) = 2 * 256 * 4 = 2048 blocks of 256 threads
    dim3 grid(2 * Hh * 4);
    dim3 block(256);
    hipLaunchKernelGGL(revo_kernel, grid, block, 0, stream,
                       in, w1, b1, w2, b2, w3, b3, gamma, beta, mean, var, out);
}